// Round 12
// baseline (310.112 us; speedup 1.0000x reference)
//
#include <hip/hip_runtime.h>
#include <math.h>

// Circular 3D cross-correlation via FFT, B=8, V=128.
// Z = v1 + i*v2 packed complex FFT; Hermitian split; G = F1*conj(F2); inverse.
// Storage: each transformed axis in bit-reversed order; pairs k<->-k via
// bitrev7 per axis (same convention as all passing rounds).
//
// Round-15 mechanics (K3 pair-sharing):
//  * Round-11 K3 was VALU-bound (VALUBusy 63%, HBM 5%): every block ran a
//    full y-IFFT128 for all 128 columns, with B-columns recomputing the IFFT
//    of the SAME stored line as their mirror A-column (Hermitian pair).
//    Now pass-1 runs ONE inv128 per pair: group g<63 transforms A-line
//    xA=bitrev7(g+1) and scatters to xA and xB=bitrev7(128-(g+1)) (conj,
//    same y -- identity verified in round 11); group 63 does self x=0,1.
//    65 IFFTs/block instead of 128 (-33% per-thread VALU).
//  * K1/K2 unchanged from round-11 (K1: fused-combine staging, dwordx4
//    stores; K2: A-slice-only inv+store; all traffic bit-exact).

#define V    128
#define V2   16384
#define V3   2097152
#define NB   8
#define PR1  134            // K1 rows pitch (float2): [64][134] = 68608 B
#define PC1  66             // K1 repack pitch (float2): [128][66] (aliased)
#define P3Q  130            // K3 half-tile pitch (float2): [64][130] = 66560 B
#define PH3  34             // K2 LDS pitch (float2) for 32-wide slices
#define SLICE (V * PH3)     // 4352 float2 = 34816 B

__device__ __forceinline__ int bitrev7(int x) {
  return (int)(__brev((unsigned)x) >> 25);
}
__device__ __forceinline__ int negrev(int j) {
  int k = bitrev7(j);
  return bitrev7((V - k) & (V - 1));
}

__device__ __forceinline__ float2 cmul(float2 a, float2 b) {
  return make_float2(a.x * b.x - a.y * b.y, a.x * b.y + a.y * b.x);
}
__device__ __forceinline__ float2 cmulc(float2 a, float2 b) {  // a * conj(b)
  return make_float2(a.x * b.x + a.y * b.y, a.y * b.x - a.x * b.y);
}
__device__ __forceinline__ float2 csqr(float2 a) {
  return make_float2(a.x * a.x - a.y * a.y, 2.0f * a.x * a.y);
}
__device__ __forceinline__ float2 f2add(float2 a, float2 b) {
  return make_float2(a.x + b.x, a.y + b.y);
}
__device__ __forceinline__ float2 f2sub(float2 a, float2 b) {
  return make_float2(a.x - b.x, a.y - b.y);
}
__device__ __forceinline__ float2 NI(float2 z) { return make_float2(z.y, -z.x); }  // z*(-i)
__device__ __forceinline__ float2 PI(float2 z) { return make_float2(-z.y, z.x); }  // z*(+i)

#define KC1 0.92387953251128675613f   // cos(pi/8)
#define KS1 0.38268343236508977173f   // sin(pi/8)
#define KR  0.70710678118654752440f

// DPP lane exchange: 0xB1 = quad_perm[1,0,3,2] (lane^1),
// 0x4E = quad_perm[2,3,0,1] (lane^2), 0x141 = row_half_mirror (lane^7).
template <int CTRL>
__device__ __forceinline__ float dppf(float v) {
  return __int_as_float(
      __builtin_amdgcn_update_dpp(0, __float_as_int(v), CTRL, 0xF, 0xF, true));
}
template <int CTRL>
__device__ __forceinline__ float2 dpp2(float2 v) {
  return make_float2(dppf<CTRL>(v.x), dppf<CTRL>(v.y));
}

// FFT cores, trimmed twiddle state. Lane lq (0..7 in group) holds elements
// n = e + 8j, e = lq ^ 3*bit2(lq). 128-pt: j=0..15; 64-pt: j=0..7.
// Cross-lane stages h=4,2,1 via DPP masks 7,2,1 (shared by both sizes).
struct WFT {
  float2 w1, w2, w4, w8, ts4, ts2;
  float sg4, sg2, sg1;
  bool up4, up2;
  int e;

  __device__ void init(int lq) {
    e = lq ^ (((lq >> 2) & 1) * 3);
    const float k = -6.28318530717958647692f / 128.0f;
    w1 = make_float2(cosf(k * (float)e), sinf(k * (float)e));  // W128^e
    w2 = csqr(w1);                                             // W64^e
    w4 = csqr(w2);                                             // W32^e
    w8 = csqr(w4);                                             // W16^e
    up4 = (e >> 2) & 1;
    up2 = (e >> 1) & 1;
    const bool up1 = e & 1;
    sg4 = up4 ? -1.0f : 1.0f;
    sg2 = up2 ? -1.0f : 1.0f;
    sg1 = up1 ? -1.0f : 1.0f;
    const int m4 = e & 3;
    float2 w8p = (m4 == 0) ? make_float2(1.0f, 0.0f)
               : (m4 == 1) ? make_float2(KR, -KR)
               : (m4 == 2) ? make_float2(0.0f, -1.0f)
                           : make_float2(-KR, -KR);
    ts4 = up4 ? w8p : make_float2(1.0f, 0.0f);    // W8^{e&3} on upper half
    ts2 = (up2 && (e & 1)) ? make_float2(0.0f, -1.0f) : make_float2(1.0f, 0.0f);
  }

  // -- cross-lane stage helpers (shared fwd/inv shapes) --
  __device__ __forceinline__ void xf4(float2* c, int n) const {
#pragma unroll
    for (int j = 0; j < n; ++j) {                 // h=4 : lane^7
      float2 p = dpp2<0x141>(c[j]);
      float2 t = make_float2(fmaf(c[j].x, sg4, p.x), fmaf(c[j].y, sg4, p.y));
      c[j] = cmul(t, ts4);
    }
#pragma unroll
    for (int j = 0; j < n; ++j) {                 // h=2 : lane^2
      float2 p = dpp2<0x4E>(c[j]);
      float2 t = make_float2(fmaf(c[j].x, sg2, p.x), fmaf(c[j].y, sg2, p.y));
      c[j] = cmul(t, ts2);
    }
#pragma unroll
    for (int j = 0; j < n; ++j) {                 // h=1 : lane^1 (tw = 1)
      float2 p = dpp2<0xB1>(c[j]);
      c[j] = make_float2(fmaf(c[j].x, sg1, p.x), fmaf(c[j].y, sg1, p.y));
    }
  }
  __device__ __forceinline__ void xi4(float2* c, int n) const {
#pragma unroll
    for (int j = 0; j < n; ++j) {                 // h=1
      float2 p = dpp2<0xB1>(c[j]);
      c[j] = make_float2(fmaf(c[j].x, sg1, p.x), fmaf(c[j].y, sg1, p.y));
    }
#pragma unroll
    for (int j = 0; j < n; ++j) {                 // h=2
      float2 m = cmulc(c[j], ts2);
      float2 q = make_float2(up2 ? m.x : c[j].x, up2 ? m.y : c[j].y);
      float2 p = dpp2<0x4E>(q);
      c[j] = make_float2(fmaf(q.x, sg2, p.x), fmaf(q.y, sg2, p.y));
    }
#pragma unroll
    for (int j = 0; j < n; ++j) {                 // h=4
      float2 m = cmulc(c[j], ts4);
      float2 q = make_float2(up4 ? m.x : c[j].x, up4 ? m.y : c[j].y);
      float2 p = dpp2<0x141>(q);
      c[j] = make_float2(fmaf(q.x, sg4, p.x), fmaf(q.y, sg4, p.y));
    }
  }

  __device__ __forceinline__ void fwd128(float2 c[16]) const {
    const float2 tA = cmul(w1, make_float2(KC1, -KS1));
    const float2 tB = cmul(w1, make_float2(KR, -KR));
    const float2 tC = cmul(w1, make_float2(KS1, -KC1));
#pragma unroll
    for (int j = 0; j < 8; ++j) {                 // h=64
      float2 u = c[j], v = c[j + 8];
      c[j] = f2add(u, v);
      const int q = j & 3;
      float2 tw = (q == 0) ? w1 : (q == 1) ? tA : (q == 2) ? tB : tC;
      float2 t = cmul(f2sub(u, v), tw);
      c[j + 8] = (j < 4) ? t : NI(t);
    }
    const float2 t2 = cmul(w2, make_float2(KR, -KR));
#pragma unroll
    for (int g = 0; g < 2; ++g) {                 // h=32
#pragma unroll
      for (int j0 = 0; j0 < 4; ++j0) {
        const int j = g * 8 + j0;
        float2 u = c[j], v = c[j + 4];
        c[j] = f2add(u, v);
        float2 t = cmul(f2sub(u, v), (j0 & 1) ? t2 : w2);
        c[j + 4] = (j0 < 2) ? t : NI(t);
      }
    }
    const float2 w4n = NI(w4);
#pragma unroll
    for (int g = 0; g < 4; ++g) {                 // h=16
#pragma unroll
      for (int j0 = 0; j0 < 2; ++j0) {
        const int j = g * 4 + j0;
        float2 u = c[j], v = c[j + 2];
        c[j] = f2add(u, v);
        c[j + 2] = cmul(f2sub(u, v), j0 ? w4n : w4);
      }
    }
#pragma unroll
    for (int j = 0; j < 16; j += 2) {             // h=8
      float2 u = c[j], v = c[j + 1];
      c[j] = f2add(u, v);
      c[j + 1] = cmul(f2sub(u, v), w8);
    }
    xf4(c, 16);
  }

  __device__ __forceinline__ void inv128(float2 c[16]) const {
    xi4(c, 16);
#pragma unroll
    for (int j = 0; j < 16; j += 2) {             // h=8
      float2 m = cmulc(c[j + 1], w8);
      float2 u = c[j];
      c[j] = f2add(u, m);
      c[j + 1] = f2sub(u, m);
    }
#pragma unroll
    for (int g = 0; g < 4; ++g) {                 // h=16
#pragma unroll
      for (int j0 = 0; j0 < 2; ++j0) {
        const int j = g * 4 + j0;
        float2 m0 = cmulc(c[j + 2], w4);
        float2 m = j0 ? PI(m0) : m0;              // conj(NI(w4)) = conj(w4)*i
        float2 u = c[j];
        c[j] = f2add(u, m);
        c[j + 2] = f2sub(u, m);
      }
    }
    const float2 t2 = cmul(w2, make_float2(KR, -KR));
#pragma unroll
    for (int g = 0; g < 2; ++g) {                 // h=32
#pragma unroll
      for (int j0 = 0; j0 < 4; ++j0) {
        const int j = g * 8 + j0;
        float2 m0 = cmulc(c[j + 4], (j0 & 1) ? t2 : w2);
        float2 m = (j0 < 2) ? m0 : PI(m0);
        float2 u = c[j];
        c[j] = f2add(u, m);
        c[j + 4] = f2sub(u, m);
      }
    }
    const float2 tA = cmul(w1, make_float2(KC1, -KS1));
    const float2 tB = cmul(w1, make_float2(KR, -KR));
    const float2 tC = cmul(w1, make_float2(KS1, -KC1));
#pragma unroll
    for (int j = 0; j < 8; ++j) {                 // h=64
      const int q = j & 3;
      float2 tw = (q == 0) ? w1 : (q == 1) ? tA : (q == 2) ? tB : tC;
      float2 m0 = cmulc(c[j + 8], tw);
      float2 m = (j < 4) ? m0 : PI(m0);
      float2 u = c[j];
      c[j] = f2add(u, m);
      c[j + 8] = f2sub(u, m);
    }
  }

  // 64-pt forward DIF on c[8], elements n = e + 8j (w2-based chain).
  __device__ __forceinline__ void fwd64(float2 c[8]) const {
    const float2 t2 = cmul(w2, make_float2(KR, -KR));
#pragma unroll
    for (int j = 0; j < 4; ++j) {                 // h=32
      float2 u = c[j], v = c[j + 4];
      c[j] = f2add(u, v);
      float2 t = cmul(f2sub(u, v), (j & 1) ? t2 : w2);
      c[j + 4] = (j < 2) ? t : NI(t);
    }
    const float2 w4n = NI(w4);
#pragma unroll
    for (int g = 0; g < 2; ++g) {                 // h=16
#pragma unroll
      for (int j0 = 0; j0 < 2; ++j0) {
        const int j = g * 4 + j0;
        float2 u = c[j], v = c[j + 2];
        c[j] = f2add(u, v);
        c[j + 2] = cmul(f2sub(u, v), j0 ? w4n : w4);
      }
    }
#pragma unroll
    for (int j = 0; j < 8; j += 2) {              // h=8
      float2 u = c[j], v = c[j + 1];
      c[j] = f2add(u, v);
      c[j + 1] = cmul(f2sub(u, v), w8);
    }
    xf4(c, 8);
  }
};

// K1: per (b, z1, h). Cooperative float4 staging (8 lanes x 8 rows per wave)
// applies the y-combine (h=0: a+b; h=1: (a-b)*W128^r) while filling LDS.
// Then: e+8j gather from own LDS row -> fwd128 -> row write-back -> column
// reads -> fwd64 pair -> repack -> dwordx4 cooperative stores to
// Z(b, x, z1, h*64 + p).
__global__ __launch_bounds__(512) void k_fwd_xy(const float* __restrict__ v1,
                                                const float* __restrict__ v2,
                                                float2* __restrict__ Z) {
  __shared__ float2 s[64 * PR1];   // 68608 B; repacked as [128][PC1] later
  const int tid = threadIdx.x, lane = tid & 63, wave = tid >> 6;
  const int g = tid >> 3, lq = tid & 7;
  const int bz = blockIdx.x >> 1, h = blockIdx.x & 1;
  const int b = bz >> 7, z1 = bz & 127;
  WFT F;
  F.init(lq);
  const int e = F.e;
  const size_t pb = (size_t)b * V3 + (size_t)z1 * V2;
  {                                            // stage: combined rows
    const int r = tid >> 3;                    // 8 lanes per row, 8 rows/wave
    const float* p1r = v1 + pb + (size_t)r * V;
    const float* p2r = v2 + pb + (size_t)r * V;
    if (h == 0) {
#pragma unroll
      for (int it = 0; it < 4; ++it) {
        const int x = ((tid & 7) + 8 * it) << 2;   // float / float2 offset
        const float4 a  = *(const float4*)(p1r + x);
        const float4 ab = *(const float4*)(p1r + x + 64 * V);
        const float4 q  = *(const float4*)(p2r + x);
        const float4 qb = *(const float4*)(p2r + x + 64 * V);
        float2* dst = s + r * PR1 + x;
        *(float4*)(dst) =
            make_float4(a.x + ab.x, q.x + qb.x, a.y + ab.y, q.y + qb.y);
        *(float4*)(dst + 2) =
            make_float4(a.z + ab.z, q.z + qb.z, a.w + ab.w, q.w + qb.w);
      }
    } else {
      const float kk = -6.28318530717958647692f / 128.0f;
      const float2 Wr = make_float2(cosf(kk * (float)r), sinf(kk * (float)r));
#pragma unroll
      for (int it = 0; it < 4; ++it) {
        const int x = ((tid & 7) + 8 * it) << 2;
        const float4 a  = *(const float4*)(p1r + x);
        const float4 ab = *(const float4*)(p1r + x + 64 * V);
        const float4 q  = *(const float4*)(p2r + x);
        const float4 qb = *(const float4*)(p2r + x + 64 * V);
        float2* dst = s + r * PR1 + x;
        const float2 d0 = cmul(make_float2(a.x - ab.x, q.x - qb.x), Wr);
        const float2 d1 = cmul(make_float2(a.y - ab.y, q.y - qb.y), Wr);
        const float2 d2 = cmul(make_float2(a.z - ab.z, q.z - qb.z), Wr);
        const float2 d3 = cmul(make_float2(a.w - ab.w, q.w - qb.w), Wr);
        *(float4*)(dst) = make_float4(d0.x, d0.y, d1.x, d1.y);
        *(float4*)(dst + 2) = make_float4(d2.x, d2.y, d3.x, d3.y);
      }
    }
  }
  __syncthreads();
  float2 c[16];                                // x-FFT of own row (wave-local
#pragma unroll                                 // read->write, row-exclusive)
  for (int j = 0; j < 16; ++j) c[j] = s[g * PR1 + e + 8 * j];
  F.fwd128(c);
#pragma unroll
  for (int j = 0; j < 16; ++j) s[g * PR1 + e + 8 * j] = c[j];
  __syncthreads();
  float2 ca[8], cb[8];                         // columns x = g and g+64
#pragma unroll
  for (int j = 0; j < 8; ++j) {
    const int r = e + 8 * j;
    ca[j] = s[r * PR1 + g];
    cb[j] = s[r * PR1 + g + 64];
  }
  __syncthreads();                             // all column reads done
  F.fwd64(ca);
  F.fwd64(cb);
#pragma unroll
  for (int j = 0; j < 8; ++j) {                // repack: [x][p] lines
    s[g * PC1 + e + 8 * j] = ca[j];
    s[(g + 64) * PC1 + e + 8 * j] = cb[j];
  }
  __syncthreads();
  {                                            // dwordx4 stores, 2 lines/iter
    const int l2 = (lane & 31) << 1;
    for (int L = wave * 2 + (lane >> 5); L < 128; L += 16) {
      const size_t zb = ((size_t)(b * V + L) * V + z1) * V + h * 64;
      *(float4*)&Z[zb + l2] = *(const float4*)&s[L * PC1 + l2];
    }
  }
}

// K2: per (b, slice-pair). Two 128x32 (z,y) quarter-slices in LDS; fwd z-FFT
// + Hermitian combine; then inv z-FFT and store ONLY the A-slice
// (bitrev7(x) <= 64) for cross pairs -- G is Hermitian, so K3 reconstructs
// B-lines from A-lines. Self-x blocks keep both slices.
__global__ __launch_bounds__(512) void k_z_fused(float2* __restrict__ Z) {
  __shared__ float2 T[2 * SLICE];   // 69632 B -> 2 blocks/CU
  const int tid = threadIdx.x, lane = tid & 63, wave = tid >> 6;
  const int o = lane >> 3, lq = lane & 7;
  const int blk = blockIdx.x;
  const int b = blk >> 8, idx = blk & 255;
  int x0, x1, jb0, jb1;
  bool within = false;
  {
    const int h = idx >> 7, r2 = idx & 127;   // h = ky parity (storage bit6)
    if (r2 < 126) {
      const int k = (r2 >> 1) + 1, cc = r2 & 1;
      const int xa = bitrev7(k), xb = bitrev7(V - k);
      if (h == 0) { x0 = xa; x1 = xb; jb0 = cc * 32; jb1 = cc * 32; }
      else { x0 = cc ? xb : xa; x1 = cc ? xa : xb; jb0 = 64; jb1 = 96; }
    } else {
      x0 = x1 = r2 - 126;                     // self-paired x = 0 or 1
      if (h == 0) { jb0 = 0; jb1 = 32; within = true; }
      else { jb0 = 64; jb1 = 96; }
    }
  }
  const bool crossAB = (x0 != x1);
  const bool keep0 = !crossAB || (bitrev7(x0) <= 64);
  const bool keep1 = !crossAB || !keep0;
  WFT F;
  F.init(lq);
  const int e = F.e;
  const size_t base0 = (size_t)(b * V + x0) * V2 + jb0;
  const size_t base1 = (size_t)(b * V + x1) * V2 + jb1;

  for (int p = tid; p < 2048; p += 512) {       // stage in (both slices)
    const int z = p >> 4, w = (p & 15) << 1;
    *(float4*)&T[z * PH3 + w] = *(const float4*)&Z[base0 + (size_t)z * V + w];
  }
  for (int p = tid; p < 2048; p += 512) {
    const int z = p >> 4, w = (p & 15) << 1;
    *(float4*)&T[SLICE + z * PH3 + w] =
        *(const float4*)&Z[base1 + (size_t)z * V + w];
  }
  __syncthreads();

  const int col = wave * 8 + o;                 // 0..63: 2 slices x 32 cols
  const int tb = (col >> 5) * SLICE, yc = col & 31;
  float2 c[16];
#pragma unroll
  for (int j = 0; j < 16; ++j) c[j] = T[tb + (e + 8 * j) * PH3 + yc];
  F.fwd128(c);
#pragma unroll
  for (int j = 0; j < 16; ++j) T[tb + (e + 8 * j) * PH3 + yc] = c[j];
  __syncthreads();

  if (!within) {                                // combine S0 <-> S1
    for (int p = tid; p < 4096; p += 512) {
      const int z = p >> 5, t = p & 31;
      const int zm = negrev(z), tm = negrev(jb0 + t) & 31;
      const float2 a  = T[z * PH3 + t];
      const float2 bb = T[SLICE + zm * PH3 + tm];
      const float f1r = 0.5f * (a.x + bb.x), f1i = 0.5f * (a.y - bb.y);
      const float f2r = 0.5f * (a.y + bb.y), f2i = 0.5f * (bb.x - a.x);
      const float gr = f1r * f2r + f1i * f2i;
      const float gi = f1i * f2r - f1r * f2i;
      T[z * PH3 + t] = make_float2(gr, gi);
      T[SLICE + zm * PH3 + tm] = make_float2(gr, -gi);
    }
  } else {                                      // combine within each slice
    for (int p = tid; p < 8192; p += 512) {
      const int s2 = p >> 12, z = (p >> 5) & 127, t = p & 31;
      const int zm = negrev(z), tm = negrev(s2 * 32 + t) & 31;
      const int pl = z * 32 + t, pm = zm * 32 + tm;
      if (pm < pl) continue;
      const float2 a  = T[s2 * SLICE + z * PH3 + t];
      const float2 bb = T[s2 * SLICE + zm * PH3 + tm];
      const float f1r = 0.5f * (a.x + bb.x), f1i = 0.5f * (a.y - bb.y);
      const float f2r = 0.5f * (a.y + bb.y), f2i = 0.5f * (bb.x - a.x);
      const float gr = f1r * f2r + f1i * f2i;
      const float gi = f1i * f2r - f1r * f2i;
      T[s2 * SLICE + z * PH3 + t] = make_float2(gr, gi);
      if (pm != pl) T[s2 * SLICE + zm * PH3 + tm] = make_float2(gr, -gi);
    }
  }
  __syncthreads();

  {                                             // inv z-FFT on kept slices
    const bool act = (col < 32) ? keep0 : keep1;
    if (act) {
#pragma unroll
      for (int j = 0; j < 16; ++j) c[j] = T[tb + (e + 8 * j) * PH3 + yc];
      F.inv128(c);
#pragma unroll
      for (int j = 0; j < 16; ++j) T[tb + (e + 8 * j) * PH3 + yc] = c[j];
    }
  }
  __syncthreads();

  if (keep0) {
    for (int p = tid; p < 2048; p += 512) {     // stage out slice 0
      const int z = p >> 4, w = (p & 15) << 1;
      *(float4*)&Z[base0 + (size_t)z * V + w] = *(const float4*)&T[z * PH3 + w];
    }
  }
  if (keep1) {
    for (int p = tid; p < 2048; p += 512) {     // stage out slice 1
      const int z = p >> 4, w = (p & 15) << 1;
      *(float4*)&Z[base1 + (size_t)z * V + w] =
          *(const float4*)&T[SLICE + z * PH3 + w];
    }
  }
}

// K3: per (b, z1, hp) half. Pass 1 (pair-shared): group g<63 runs ONE
// y-IFFT128 of A-line xA=bitrev7(g+1) and scatters its hp-half to columns
// xA and xB=bitrev7(128-(g+1)) (conj, same y -- Hermitian, z spatial);
// group 63 handles self columns x=0,1. Pass 2: x-IFFT128 rows, real*sc
// in-row f32 repack, dwordx4 cooperative stores to out(b, z1, hp*64+r, x).
__global__ __launch_bounds__(512) void k_inv_xy(const float2* __restrict__ Z,
                                                float* __restrict__ out) {
  __shared__ float2 s[64 * P3Q];  // 66560 B -> 2 blocks/CU
  const int tid = threadIdx.x, lane = tid & 63, wave = tid >> 6;
  const int g = tid >> 3, lq = tid & 7;
  const int r8 = blockIdx.x & 7, hp = (blockIdx.x >> 3) & 1;
  const int unit = (blockIdx.x >> 4) * 8 + r8;    // (b,z1) in [0,1024)
  const int b = unit >> 7, z1 = unit & 127;
  WFT F;
  F.init(lq);
  const int e = F.e;
  float2 c[16];
  if (g < 63) {                                // pair: 1 IFFT -> 2 columns
    const int k = g + 1;
    const int xA = bitrev7(k), xB = bitrev7(V - k);
    const size_t zb = ((size_t)(b * V + xA) * V + z1) * V;
#pragma unroll
    for (int j = 0; j < 16; ++j) c[j] = Z[zb + e + 8 * j];
    F.inv128(c);                               // natural y at e+8j
    if (hp == 0) {                             // keep y in [0,64)
#pragma unroll
      for (int jj = 0; jj < 8; ++jj) {
        const float2 v = c[jj];
        s[(e + 8 * jj) * P3Q + xA] = v;
        s[(e + 8 * jj) * P3Q + xB] = make_float2(v.x, -v.y);
      }
    } else {                                   // keep y in [64,128)
#pragma unroll
      for (int jj = 0; jj < 8; ++jj) {
        const float2 v = c[jj + 8];
        s[(e + 8 * jj) * P3Q + xA] = v;
        s[(e + 8 * jj) * P3Q + xB] = make_float2(v.x, -v.y);
      }
    }
  } else {                                     // g == 63: self x = 0, 1
#pragma unroll 1
    for (int sx = 0; sx < 2; ++sx) {
      const size_t zb = ((size_t)(b * V + sx) * V + z1) * V;
#pragma unroll
      for (int j = 0; j < 16; ++j) c[j] = Z[zb + e + 8 * j];
      F.inv128(c);
      if (hp == 0) {
#pragma unroll
        for (int jj = 0; jj < 8; ++jj) s[(e + 8 * jj) * P3Q + sx] = c[jj];
      } else {
#pragma unroll
        for (int jj = 0; jj < 8; ++jj) s[(e + 8 * jj) * P3Q + sx] = c[jj + 8];
      }
    }
  }
  __syncthreads();
  const float sc = 1.0f / 2097152.0f;          // 1/V^3
  {                                            // pass 2: row y_local = g
#pragma unroll
    for (int j = 0; j < 16; ++j) c[j] = s[g * P3Q + e + 8 * j];
    F.inv128(c);                               // natural x at e+8j
    float* fr = (float*)(s + g * P3Q);         // in-row f32 repack (row-
#pragma unroll                                 // exclusive per group)
    for (int j = 0; j < 16; ++j) fr[e + 8 * j] = c[j].x * sc;
  }
  __syncthreads();
  {                                            // dwordx4: 2 contig rows/iter
    const int col = (lane & 31) << 2;
    for (int r2 = wave; r2 < 32; r2 += 8) {
      const int row = 2 * r2 + (lane >> 5);
      const size_t gg =
          (size_t)b * V3 + (size_t)z1 * V2 + (size_t)(hp * 64 + row) * V;
      *(float4*)&out[gg + col] =
          *(const float4*)((const float*)(s + row * P3Q) + col);
    }
  }
}

extern "C" void kernel_launch(void* const* d_in, const int* in_sizes, int n_in,
                              void* d_out, int out_size, void* d_ws, size_t ws_size,
                              hipStream_t stream) {
  const float* v1 = (const float*)d_in[0];
  const float* v2 = (const float*)d_in[1];
  float* out = (float*)d_out;
  float2* Z  = (float2*)d_ws;  // NB*V3*8 = 128 MiB

  k_fwd_xy<<<NB * V * 2, 512, 0, stream>>>(v1, v2, Z);   // y-halves
  k_z_fused<<<NB * 256, 512, 0, stream>>>(Z);            // slice pairs
  k_inv_xy<<<NB * V * 2, 512, 0, stream>>>(Z, out);      // y-halves
}

// Round 13
// 282.018 us; speedup vs baseline: 1.0996x; 1.0996x over previous
//
#include <hip/hip_runtime.h>
#include <math.h>

// Circular 3D cross-correlation via FFT, B=8, V=128.
// Z = v1 + i*v2 packed complex FFT; Hermitian split; G = F1*conj(F2); inverse.
// Storage: each transformed axis in bit-reversed order; pairs k<->-k via
// bitrev7 per axis (same convention as all passing rounds).
//
// Round-16 mechanics (balanced K3 pair-sharing):
//  * Round-12's pair-share regressed: group 63 ran 2 serial IFFTs (barrier
//    imbalance) and bitrev'd scatter columns aliased to ~2 banks (7-way
//    conflicts). Fix: the A-line set {bitrev7(x)<=64} is exactly
//    {even x} u {0,1}. Group g handles even column 2g: one inv128, writes
//    col 2g and odd partner negrev(2g) (conj, same y). negrev of consecutive
//    even columns spreads over all odd low-bit residues -> ~2/bank. The two
//    self lines x=0,1 have REAL y-IFFTs (self-conjugate), so group 0 packs
//    L0 + i*L1 into ONE IFFT (Re->col0, Im->col1). Every group: exactly 1
//    IFFT; pass-1 critical path 1 IFFT (was 2).
//  * K1/K2 unchanged from round-11 (bit-exact traffic, A-slice-only K2).

#define V    128
#define V2   16384
#define V3   2097152
#define NB   8
#define PR1  134            // K1 rows pitch (float2): [64][134] = 68608 B
#define PC1  66             // K1 repack pitch (float2): [128][66] (aliased)
#define P3Q  130            // K3 half-tile pitch (float2): [64][130] = 66560 B
#define PH3  34             // K2 LDS pitch (float2) for 32-wide slices
#define SLICE (V * PH3)     // 4352 float2 = 34816 B

__device__ __forceinline__ int bitrev7(int x) {
  return (int)(__brev((unsigned)x) >> 25);
}
__device__ __forceinline__ int negrev(int j) {
  int k = bitrev7(j);
  return bitrev7((V - k) & (V - 1));
}

__device__ __forceinline__ float2 cmul(float2 a, float2 b) {
  return make_float2(a.x * b.x - a.y * b.y, a.x * b.y + a.y * b.x);
}
__device__ __forceinline__ float2 cmulc(float2 a, float2 b) {  // a * conj(b)
  return make_float2(a.x * b.x + a.y * b.y, a.y * b.x - a.x * b.y);
}
__device__ __forceinline__ float2 csqr(float2 a) {
  return make_float2(a.x * a.x - a.y * a.y, 2.0f * a.x * a.y);
}
__device__ __forceinline__ float2 f2add(float2 a, float2 b) {
  return make_float2(a.x + b.x, a.y + b.y);
}
__device__ __forceinline__ float2 f2sub(float2 a, float2 b) {
  return make_float2(a.x - b.x, a.y - b.y);
}
__device__ __forceinline__ float2 NI(float2 z) { return make_float2(z.y, -z.x); }  // z*(-i)
__device__ __forceinline__ float2 PI(float2 z) { return make_float2(-z.y, z.x); }  // z*(+i)

#define KC1 0.92387953251128675613f   // cos(pi/8)
#define KS1 0.38268343236508977173f   // sin(pi/8)
#define KR  0.70710678118654752440f

// DPP lane exchange: 0xB1 = quad_perm[1,0,3,2] (lane^1),
// 0x4E = quad_perm[2,3,0,1] (lane^2), 0x141 = row_half_mirror (lane^7).
template <int CTRL>
__device__ __forceinline__ float dppf(float v) {
  return __int_as_float(
      __builtin_amdgcn_update_dpp(0, __float_as_int(v), CTRL, 0xF, 0xF, true));
}
template <int CTRL>
__device__ __forceinline__ float2 dpp2(float2 v) {
  return make_float2(dppf<CTRL>(v.x), dppf<CTRL>(v.y));
}

// FFT cores, trimmed twiddle state. Lane lq (0..7 in group) holds elements
// n = e + 8j, e = lq ^ 3*bit2(lq). 128-pt: j=0..15; 64-pt: j=0..7.
// Cross-lane stages h=4,2,1 via DPP masks 7,2,1 (shared by both sizes).
struct WFT {
  float2 w1, w2, w4, w8, ts4, ts2;
  float sg4, sg2, sg1;
  bool up4, up2;
  int e;

  __device__ void init(int lq) {
    e = lq ^ (((lq >> 2) & 1) * 3);
    const float k = -6.28318530717958647692f / 128.0f;
    w1 = make_float2(cosf(k * (float)e), sinf(k * (float)e));  // W128^e
    w2 = csqr(w1);                                             // W64^e
    w4 = csqr(w2);                                             // W32^e
    w8 = csqr(w4);                                             // W16^e
    up4 = (e >> 2) & 1;
    up2 = (e >> 1) & 1;
    const bool up1 = e & 1;
    sg4 = up4 ? -1.0f : 1.0f;
    sg2 = up2 ? -1.0f : 1.0f;
    sg1 = up1 ? -1.0f : 1.0f;
    const int m4 = e & 3;
    float2 w8p = (m4 == 0) ? make_float2(1.0f, 0.0f)
               : (m4 == 1) ? make_float2(KR, -KR)
               : (m4 == 2) ? make_float2(0.0f, -1.0f)
                           : make_float2(-KR, -KR);
    ts4 = up4 ? w8p : make_float2(1.0f, 0.0f);    // W8^{e&3} on upper half
    ts2 = (up2 && (e & 1)) ? make_float2(0.0f, -1.0f) : make_float2(1.0f, 0.0f);
  }

  // -- cross-lane stage helpers (shared fwd/inv shapes) --
  __device__ __forceinline__ void xf4(float2* c, int n) const {
#pragma unroll
    for (int j = 0; j < n; ++j) {                 // h=4 : lane^7
      float2 p = dpp2<0x141>(c[j]);
      float2 t = make_float2(fmaf(c[j].x, sg4, p.x), fmaf(c[j].y, sg4, p.y));
      c[j] = cmul(t, ts4);
    }
#pragma unroll
    for (int j = 0; j < n; ++j) {                 // h=2 : lane^2
      float2 p = dpp2<0x4E>(c[j]);
      float2 t = make_float2(fmaf(c[j].x, sg2, p.x), fmaf(c[j].y, sg2, p.y));
      c[j] = cmul(t, ts2);
    }
#pragma unroll
    for (int j = 0; j < n; ++j) {                 // h=1 : lane^1 (tw = 1)
      float2 p = dpp2<0xB1>(c[j]);
      c[j] = make_float2(fmaf(c[j].x, sg1, p.x), fmaf(c[j].y, sg1, p.y));
    }
  }
  __device__ __forceinline__ void xi4(float2* c, int n) const {
#pragma unroll
    for (int j = 0; j < n; ++j) {                 // h=1
      float2 p = dpp2<0xB1>(c[j]);
      c[j] = make_float2(fmaf(c[j].x, sg1, p.x), fmaf(c[j].y, sg1, p.y));
    }
#pragma unroll
    for (int j = 0; j < n; ++j) {                 // h=2
      float2 m = cmulc(c[j], ts2);
      float2 q = make_float2(up2 ? m.x : c[j].x, up2 ? m.y : c[j].y);
      float2 p = dpp2<0x4E>(q);
      c[j] = make_float2(fmaf(q.x, sg2, p.x), fmaf(q.y, sg2, p.y));
    }
#pragma unroll
    for (int j = 0; j < n; ++j) {                 // h=4
      float2 m = cmulc(c[j], ts4);
      float2 q = make_float2(up4 ? m.x : c[j].x, up4 ? m.y : c[j].y);
      float2 p = dpp2<0x141>(q);
      c[j] = make_float2(fmaf(q.x, sg4, p.x), fmaf(q.y, sg4, p.y));
    }
  }

  __device__ __forceinline__ void fwd128(float2 c[16]) const {
    const float2 tA = cmul(w1, make_float2(KC1, -KS1));
    const float2 tB = cmul(w1, make_float2(KR, -KR));
    const float2 tC = cmul(w1, make_float2(KS1, -KC1));
#pragma unroll
    for (int j = 0; j < 8; ++j) {                 // h=64
      float2 u = c[j], v = c[j + 8];
      c[j] = f2add(u, v);
      const int q = j & 3;
      float2 tw = (q == 0) ? w1 : (q == 1) ? tA : (q == 2) ? tB : tC;
      float2 t = cmul(f2sub(u, v), tw);
      c[j + 8] = (j < 4) ? t : NI(t);
    }
    const float2 t2 = cmul(w2, make_float2(KR, -KR));
#pragma unroll
    for (int g = 0; g < 2; ++g) {                 // h=32
#pragma unroll
      for (int j0 = 0; j0 < 4; ++j0) {
        const int j = g * 8 + j0;
        float2 u = c[j], v = c[j + 4];
        c[j] = f2add(u, v);
        float2 t = cmul(f2sub(u, v), (j0 & 1) ? t2 : w2);
        c[j + 4] = (j0 < 2) ? t : NI(t);
      }
    }
    const float2 w4n = NI(w4);
#pragma unroll
    for (int g = 0; g < 4; ++g) {                 // h=16
#pragma unroll
      for (int j0 = 0; j0 < 2; ++j0) {
        const int j = g * 4 + j0;
        float2 u = c[j], v = c[j + 2];
        c[j] = f2add(u, v);
        c[j + 2] = cmul(f2sub(u, v), j0 ? w4n : w4);
      }
    }
#pragma unroll
    for (int j = 0; j < 16; j += 2) {             // h=8
      float2 u = c[j], v = c[j + 1];
      c[j] = f2add(u, v);
      c[j + 1] = cmul(f2sub(u, v), w8);
    }
    xf4(c, 16);
  }

  __device__ __forceinline__ void inv128(float2 c[16]) const {
    xi4(c, 16);
#pragma unroll
    for (int j = 0; j < 16; j += 2) {             // h=8
      float2 m = cmulc(c[j + 1], w8);
      float2 u = c[j];
      c[j] = f2add(u, m);
      c[j + 1] = f2sub(u, m);
    }
#pragma unroll
    for (int g = 0; g < 4; ++g) {                 // h=16
#pragma unroll
      for (int j0 = 0; j0 < 2; ++j0) {
        const int j = g * 4 + j0;
        float2 m0 = cmulc(c[j + 2], w4);
        float2 m = j0 ? PI(m0) : m0;              // conj(NI(w4)) = conj(w4)*i
        float2 u = c[j];
        c[j] = f2add(u, m);
        c[j + 2] = f2sub(u, m);
      }
    }
    const float2 t2 = cmul(w2, make_float2(KR, -KR));
#pragma unroll
    for (int g = 0; g < 2; ++g) {                 // h=32
#pragma unroll
      for (int j0 = 0; j0 < 4; ++j0) {
        const int j = g * 8 + j0;
        float2 m0 = cmulc(c[j + 4], (j0 & 1) ? t2 : w2);
        float2 m = (j0 < 2) ? m0 : PI(m0);
        float2 u = c[j];
        c[j] = f2add(u, m);
        c[j + 4] = f2sub(u, m);
      }
    }
    const float2 tA = cmul(w1, make_float2(KC1, -KS1));
    const float2 tB = cmul(w1, make_float2(KR, -KR));
    const float2 tC = cmul(w1, make_float2(KS1, -KC1));
#pragma unroll
    for (int j = 0; j < 8; ++j) {                 // h=64
      const int q = j & 3;
      float2 tw = (q == 0) ? w1 : (q == 1) ? tA : (q == 2) ? tB : tC;
      float2 m0 = cmulc(c[j + 8], tw);
      float2 m = (j < 4) ? m0 : PI(m0);
      float2 u = c[j];
      c[j] = f2add(u, m);
      c[j + 8] = f2sub(u, m);
    }
  }

  // 64-pt forward DIF on c[8], elements n = e + 8j (w2-based chain).
  __device__ __forceinline__ void fwd64(float2 c[8]) const {
    const float2 t2 = cmul(w2, make_float2(KR, -KR));
#pragma unroll
    for (int j = 0; j < 4; ++j) {                 // h=32
      float2 u = c[j], v = c[j + 4];
      c[j] = f2add(u, v);
      float2 t = cmul(f2sub(u, v), (j & 1) ? t2 : w2);
      c[j + 4] = (j < 2) ? t : NI(t);
    }
    const float2 w4n = NI(w4);
#pragma unroll
    for (int g = 0; g < 2; ++g) {                 // h=16
#pragma unroll
      for (int j0 = 0; j0 < 2; ++j0) {
        const int j = g * 4 + j0;
        float2 u = c[j], v = c[j + 2];
        c[j] = f2add(u, v);
        c[j + 2] = cmul(f2sub(u, v), j0 ? w4n : w4);
      }
    }
#pragma unroll
    for (int j = 0; j < 8; j += 2) {              // h=8
      float2 u = c[j], v = c[j + 1];
      c[j] = f2add(u, v);
      c[j + 1] = cmul(f2sub(u, v), w8);
    }
    xf4(c, 8);
  }
};

// K1: per (b, z1, h). Cooperative float4 staging (8 lanes x 8 rows per wave)
// applies the y-combine (h=0: a+b; h=1: (a-b)*W128^r) while filling LDS.
// Then: e+8j gather from own LDS row -> fwd128 -> row write-back -> column
// reads -> fwd64 pair -> repack -> dwordx4 cooperative stores to
// Z(b, x, z1, h*64 + p).
__global__ __launch_bounds__(512) void k_fwd_xy(const float* __restrict__ v1,
                                                const float* __restrict__ v2,
                                                float2* __restrict__ Z) {
  __shared__ float2 s[64 * PR1];   // 68608 B; repacked as [128][PC1] later
  const int tid = threadIdx.x, lane = tid & 63, wave = tid >> 6;
  const int g = tid >> 3, lq = tid & 7;
  const int bz = blockIdx.x >> 1, h = blockIdx.x & 1;
  const int b = bz >> 7, z1 = bz & 127;
  WFT F;
  F.init(lq);
  const int e = F.e;
  const size_t pb = (size_t)b * V3 + (size_t)z1 * V2;
  {                                            // stage: combined rows
    const int r = tid >> 3;                    // 8 lanes per row, 8 rows/wave
    const float* p1r = v1 + pb + (size_t)r * V;
    const float* p2r = v2 + pb + (size_t)r * V;
    if (h == 0) {
#pragma unroll
      for (int it = 0; it < 4; ++it) {
        const int x = ((tid & 7) + 8 * it) << 2;   // float / float2 offset
        const float4 a  = *(const float4*)(p1r + x);
        const float4 ab = *(const float4*)(p1r + x + 64 * V);
        const float4 q  = *(const float4*)(p2r + x);
        const float4 qb = *(const float4*)(p2r + x + 64 * V);
        float2* dst = s + r * PR1 + x;
        *(float4*)(dst) =
            make_float4(a.x + ab.x, q.x + qb.x, a.y + ab.y, q.y + qb.y);
        *(float4*)(dst + 2) =
            make_float4(a.z + ab.z, q.z + qb.z, a.w + ab.w, q.w + qb.w);
      }
    } else {
      const float kk = -6.28318530717958647692f / 128.0f;
      const float2 Wr = make_float2(cosf(kk * (float)r), sinf(kk * (float)r));
#pragma unroll
      for (int it = 0; it < 4; ++it) {
        const int x = ((tid & 7) + 8 * it) << 2;
        const float4 a  = *(const float4*)(p1r + x);
        const float4 ab = *(const float4*)(p1r + x + 64 * V);
        const float4 q  = *(const float4*)(p2r + x);
        const float4 qb = *(const float4*)(p2r + x + 64 * V);
        float2* dst = s + r * PR1 + x;
        const float2 d0 = cmul(make_float2(a.x - ab.x, q.x - qb.x), Wr);
        const float2 d1 = cmul(make_float2(a.y - ab.y, q.y - qb.y), Wr);
        const float2 d2 = cmul(make_float2(a.z - ab.z, q.z - qb.z), Wr);
        const float2 d3 = cmul(make_float2(a.w - ab.w, q.w - qb.w), Wr);
        *(float4*)(dst) = make_float4(d0.x, d0.y, d1.x, d1.y);
        *(float4*)(dst + 2) = make_float4(d2.x, d2.y, d3.x, d3.y);
      }
    }
  }
  __syncthreads();
  float2 c[16];                                // x-FFT of own row (wave-local
#pragma unroll                                 // read->write, row-exclusive)
  for (int j = 0; j < 16; ++j) c[j] = s[g * PR1 + e + 8 * j];
  F.fwd128(c);
#pragma unroll
  for (int j = 0; j < 16; ++j) s[g * PR1 + e + 8 * j] = c[j];
  __syncthreads();
  float2 ca[8], cb[8];                         // columns x = g and g+64
#pragma unroll
  for (int j = 0; j < 8; ++j) {
    const int r = e + 8 * j;
    ca[j] = s[r * PR1 + g];
    cb[j] = s[r * PR1 + g + 64];
  }
  __syncthreads();                             // all column reads done
  F.fwd64(ca);
  F.fwd64(cb);
#pragma unroll
  for (int j = 0; j < 8; ++j) {                // repack: [x][p] lines
    s[g * PC1 + e + 8 * j] = ca[j];
    s[(g + 64) * PC1 + e + 8 * j] = cb[j];
  }
  __syncthreads();
  {                                            // dwordx4 stores, 2 lines/iter
    const int l2 = (lane & 31) << 1;
    for (int L = wave * 2 + (lane >> 5); L < 128; L += 16) {
      const size_t zb = ((size_t)(b * V + L) * V + z1) * V + h * 64;
      *(float4*)&Z[zb + l2] = *(const float4*)&s[L * PC1 + l2];
    }
  }
}

// K2: per (b, slice-pair). Two 128x32 (z,y) quarter-slices in LDS; fwd z-FFT
// + Hermitian combine; then inv z-FFT and store ONLY the A-slice
// (bitrev7(x) <= 64) for cross pairs -- G is Hermitian, so K3 reconstructs
// B-lines from A-lines. Self-x blocks keep both slices.
__global__ __launch_bounds__(512) void k_z_fused(float2* __restrict__ Z) {
  __shared__ float2 T[2 * SLICE];   // 69632 B -> 2 blocks/CU
  const int tid = threadIdx.x, lane = tid & 63, wave = tid >> 6;
  const int o = lane >> 3, lq = lane & 7;
  const int blk = blockIdx.x;
  const int b = blk >> 8, idx = blk & 255;
  int x0, x1, jb0, jb1;
  bool within = false;
  {
    const int h = idx >> 7, r2 = idx & 127;   // h = ky parity (storage bit6)
    if (r2 < 126) {
      const int k = (r2 >> 1) + 1, cc = r2 & 1;
      const int xa = bitrev7(k), xb = bitrev7(V - k);
      if (h == 0) { x0 = xa; x1 = xb; jb0 = cc * 32; jb1 = cc * 32; }
      else { x0 = cc ? xb : xa; x1 = cc ? xa : xb; jb0 = 64; jb1 = 96; }
    } else {
      x0 = x1 = r2 - 126;                     // self-paired x = 0 or 1
      if (h == 0) { jb0 = 0; jb1 = 32; within = true; }
      else { jb0 = 64; jb1 = 96; }
    }
  }
  const bool crossAB = (x0 != x1);
  const bool keep0 = !crossAB || (bitrev7(x0) <= 64);
  const bool keep1 = !crossAB || !keep0;
  WFT F;
  F.init(lq);
  const int e = F.e;
  const size_t base0 = (size_t)(b * V + x0) * V2 + jb0;
  const size_t base1 = (size_t)(b * V + x1) * V2 + jb1;

  for (int p = tid; p < 2048; p += 512) {       // stage in (both slices)
    const int z = p >> 4, w = (p & 15) << 1;
    *(float4*)&T[z * PH3 + w] = *(const float4*)&Z[base0 + (size_t)z * V + w];
  }
  for (int p = tid; p < 2048; p += 512) {
    const int z = p >> 4, w = (p & 15) << 1;
    *(float4*)&T[SLICE + z * PH3 + w] =
        *(const float4*)&Z[base1 + (size_t)z * V + w];
  }
  __syncthreads();

  const int col = wave * 8 + o;                 // 0..63: 2 slices x 32 cols
  const int tb = (col >> 5) * SLICE, yc = col & 31;
  float2 c[16];
#pragma unroll
  for (int j = 0; j < 16; ++j) c[j] = T[tb + (e + 8 * j) * PH3 + yc];
  F.fwd128(c);
#pragma unroll
  for (int j = 0; j < 16; ++j) T[tb + (e + 8 * j) * PH3 + yc] = c[j];
  __syncthreads();

  if (!within) {                                // combine S0 <-> S1
    for (int p = tid; p < 4096; p += 512) {
      const int z = p >> 5, t = p & 31;
      const int zm = negrev(z), tm = negrev(jb0 + t) & 31;
      const float2 a  = T[z * PH3 + t];
      const float2 bb = T[SLICE + zm * PH3 + tm];
      const float f1r = 0.5f * (a.x + bb.x), f1i = 0.5f * (a.y - bb.y);
      const float f2r = 0.5f * (a.y + bb.y), f2i = 0.5f * (bb.x - a.x);
      const float gr = f1r * f2r + f1i * f2i;
      const float gi = f1i * f2r - f1r * f2i;
      T[z * PH3 + t] = make_float2(gr, gi);
      T[SLICE + zm * PH3 + tm] = make_float2(gr, -gi);
    }
  } else {                                      // combine within each slice
    for (int p = tid; p < 8192; p += 512) {
      const int s2 = p >> 12, z = (p >> 5) & 127, t = p & 31;
      const int zm = negrev(z), tm = negrev(s2 * 32 + t) & 31;
      const int pl = z * 32 + t, pm = zm * 32 + tm;
      if (pm < pl) continue;
      const float2 a  = T[s2 * SLICE + z * PH3 + t];
      const float2 bb = T[s2 * SLICE + zm * PH3 + tm];
      const float f1r = 0.5f * (a.x + bb.x), f1i = 0.5f * (a.y - bb.y);
      const float f2r = 0.5f * (a.y + bb.y), f2i = 0.5f * (bb.x - a.x);
      const float gr = f1r * f2r + f1i * f2i;
      const float gi = f1i * f2r - f1r * f2i;
      T[s2 * SLICE + z * PH3 + t] = make_float2(gr, gi);
      if (pm != pl) T[s2 * SLICE + zm * PH3 + tm] = make_float2(gr, -gi);
    }
  }
  __syncthreads();

  {                                             // inv z-FFT on kept slices
    const bool act = (col < 32) ? keep0 : keep1;
    if (act) {
#pragma unroll
      for (int j = 0; j < 16; ++j) c[j] = T[tb + (e + 8 * j) * PH3 + yc];
      F.inv128(c);
#pragma unroll
      for (int j = 0; j < 16; ++j) T[tb + (e + 8 * j) * PH3 + yc] = c[j];
    }
  }
  __syncthreads();

  if (keep0) {
    for (int p = tid; p < 2048; p += 512) {     // stage out slice 0
      const int z = p >> 4, w = (p & 15) << 1;
      *(float4*)&Z[base0 + (size_t)z * V + w] = *(const float4*)&T[z * PH3 + w];
    }
  }
  if (keep1) {
    for (int p = tid; p < 2048; p += 512) {     // stage out slice 1
      const int z = p >> 4, w = (p & 15) << 1;
      *(float4*)&Z[base1 + (size_t)z * V + w] =
          *(const float4*)&T[SLICE + z * PH3 + w];
    }
  }
}

// K3: per (b, z1, hp) half. Pass 1 (balanced pair-share): group g in [0,64)
// owns even column x=2g. g>=1: one y-IFFT128 of stored line 2g; write col 2g
// and odd partner negrev(2g) (conj, same y -- Hermitian, z spatial). g==0:
// lines 0 and 1 are self-conjugate (real y-IFFTs), packed as L0 + i*L1 into
// ONE IFFT (Re->col0, Im->col1). Every group: exactly 1 inv128. Pass 2:
// x-IFFT128 rows, real*sc in-row f32 repack, dwordx4 cooperative stores.
__global__ __launch_bounds__(512) void k_inv_xy(const float2* __restrict__ Z,
                                                float* __restrict__ out) {
  __shared__ float2 s[64 * P3Q];  // 66560 B -> 2 blocks/CU
  const int tid = threadIdx.x, lane = tid & 63, wave = tid >> 6;
  const int g = tid >> 3, lq = tid & 7;
  const int r8 = blockIdx.x & 7, hp = (blockIdx.x >> 3) & 1;
  const int unit = (blockIdx.x >> 4) * 8 + r8;    // (b,z1) in [0,1024)
  const int b = unit >> 7, z1 = unit & 127;
  WFT F;
  F.init(lq);
  const int e = F.e;
  float2 c[16];
  {                                            // pass 1: even column x = 2g
    const int xA = 2 * g;
    const size_t zb0 = ((size_t)(b * V + xA) * V + z1) * V;
    if (g == 0) {                              // packed self lines 0 and 1
      const size_t zb1 = ((size_t)(b * V + 1) * V + z1) * V;
#pragma unroll
      for (int j = 0; j < 16; ++j) {
        const float2 a = Z[zb0 + e + 8 * j];
        const float2 q = Z[zb1 + e + 8 * j];
        c[j] = make_float2(a.x - q.y, a.y + q.x);   // L0 + i*L1
      }
    } else {
#pragma unroll
      for (int j = 0; j < 16; ++j) c[j] = Z[zb0 + e + 8 * j];
    }
    F.inv128(c);                               // natural y at e+8j
    const int xB = negrev(xA);                 // odd partner (g>=1)
    if (g == 0) {
      if (hp == 0) {
#pragma unroll
        for (int jj = 0; jj < 8; ++jj) {
          s[(e + 8 * jj) * P3Q + 0] = make_float2(c[jj].x, 0.0f);
          s[(e + 8 * jj) * P3Q + 1] = make_float2(c[jj].y, 0.0f);
        }
      } else {
#pragma unroll
        for (int jj = 0; jj < 8; ++jj) {
          s[(e + 8 * jj) * P3Q + 0] = make_float2(c[jj + 8].x, 0.0f);
          s[(e + 8 * jj) * P3Q + 1] = make_float2(c[jj + 8].y, 0.0f);
        }
      }
    } else {
      if (hp == 0) {
#pragma unroll
        for (int jj = 0; jj < 8; ++jj) {
          const float2 v = c[jj];
          s[(e + 8 * jj) * P3Q + xA] = v;
          s[(e + 8 * jj) * P3Q + xB] = make_float2(v.x, -v.y);
        }
      } else {
#pragma unroll
        for (int jj = 0; jj < 8; ++jj) {
          const float2 v = c[jj + 8];
          s[(e + 8 * jj) * P3Q + xA] = v;
          s[(e + 8 * jj) * P3Q + xB] = make_float2(v.x, -v.y);
        }
      }
    }
  }
  __syncthreads();
  const float sc = 1.0f / 2097152.0f;          // 1/V^3
  {                                            // pass 2: row y_local = g
#pragma unroll
    for (int j = 0; j < 16; ++j) c[j] = s[g * P3Q + e + 8 * j];
    F.inv128(c);                               // natural x at e+8j
    float* fr = (float*)(s + g * P3Q);         // in-row f32 repack (row-
#pragma unroll                                 // exclusive per group)
    for (int j = 0; j < 16; ++j) fr[e + 8 * j] = c[j].x * sc;
  }
  __syncthreads();
  {                                            // dwordx4: 2 contig rows/iter
    const int col = (lane & 31) << 2;
    for (int r2 = wave; r2 < 32; r2 += 8) {
      const int row = 2 * r2 + (lane >> 5);
      const size_t gg =
          (size_t)b * V3 + (size_t)z1 * V2 + (size_t)(hp * 64 + row) * V;
      *(float4*)&out[gg + col] =
          *(const float4*)((const float*)(s + row * P3Q) + col);
    }
  }
}

extern "C" void kernel_launch(void* const* d_in, const int* in_sizes, int n_in,
                              void* d_out, int out_size, void* d_ws, size_t ws_size,
                              hipStream_t stream) {
  const float* v1 = (const float*)d_in[0];
  const float* v2 = (const float*)d_in[1];
  float* out = (float*)d_out;
  float2* Z  = (float2*)d_ws;  // NB*V3*8 = 128 MiB

  k_fwd_xy<<<NB * V * 2, 512, 0, stream>>>(v1, v2, Z);   // y-halves
  k_z_fused<<<NB * 256, 512, 0, stream>>>(Z);            // slice pairs
  k_inv_xy<<<NB * V * 2, 512, 0, stream>>>(Z, out);      // y-halves
}